// Round 19
// baseline (109.087 us; speedup 1.0000x reference)
//
#include <hip/hip_runtime.h>
#include <hip/hip_fp16.h>

#define H_IMG 256
#define W_IMG 512
#define NPIX  (H_IMG*W_IMG)   // 131072
#define BATCH 4
#define HID   64

#define TX 32
#define TY 8
#define HX (TX+2)   // 34
#define HY (TY+2)   // 10
#define HN (HX*HY)  // 340
#define NA (6*HX)   // 204: halo rows 0-5 (chunk A); rows 6-9 = chunk B
#define LTH 256

// LDS: node-major, 64 halfs (128 B) per node, NO pad (global_load_lds writes
// linearly). Bank conflicts handled by XOR swizzle: chunk c8 of node n lives
// at halfs n*64 + ((c8 ^ (n&7))*8). Staging pre-swizzles the GLOBAL source
// chunk so the linear LDS write lands swizzled (rule: both-sides-or-neither).
// Staging is split A(rows 0-5)/B(rows 6-9): drain A, issue B, compute output
// rows 0-3 (reads halo rows 0-5 only) while B's loads fly, barrier, rows 4-7.

typedef _Float16 half8 __attribute__((ext_vector_type(8)));
typedef float v4f __attribute__((ext_vector_type(4)));

#define GLOAD16(gp, lp) \
  __builtin_amdgcn_global_load_lds((const __attribute__((address_space(1))) unsigned int*)(gp), \
                                   (__attribute__((address_space(3))) unsigned int*)(lp), 16, 0, 0)

__device__ __forceinline__ float rs1(int v, int n) {
  return rsqrtf((float)(3 - (v==0) - (v==(n-1))));   // finite for any v
}

__device__ __forceinline__ unsigned pack2(float a, float b) {
  __half2 h = __floats2half2_rn(a, b);
  return *reinterpret_cast<unsigned*>(&h);
}

// acc{L,H} += fp16{lo,hi}(hv) * s   — forced v_fma_mix_f32 (R16-proven)
__device__ __forceinline__ void fma_mix2(float& accL, float& accH, unsigned hv, float s) {
  asm("v_fma_mix_f32 %0, %2, %3, %0 op_sel:[0,0,0] op_sel_hi:[1,0,0]\n\t"
      "v_fma_mix_f32 %1, %2, %3, %1 op_sel:[1,0,0] op_sel_hi:[1,0,0]"
      : "+v"(accL), "+v"(accH)
      : "v"(hv), "v"(s));
}

// WgT[l][f][k] = fp16(Wg[l][k][f])   (R2/R8-proven)
__global__ void k_wg(const float* __restrict__ Wg, __half* __restrict__ WgT) {
  int idx = blockIdx.x * 256 + threadIdx.x;          // 3*64*64 = 12288
  int l = idx >> 12, rem = idx & 4095;
  int f = rem >> 6, k = rem & 63;
  WgT[idx] = __float2half(Wg[(l << 12) + (k << 6) + f]);
}

// Copy layer-3 WgT slice (4096 halfs) from d_out head into dead hA region
// (layer 3 writes d_out, so it must not read weights from d_out).  (R17-proven)
__global__ void k_prep2(const __half* __restrict__ src, __half* __restrict__ dst) {
  int idx = blockIdx.x * 256 + threadIdx.x;
  if (idx < 4096) dst[idx] = src[idx];
}

// One GCN layer (32x8 tile, 256 threads). FUSED stencil+GEMM for all modes.
// MODE 0: build h0 from x on the fly;  MODE 1: async-stage from hin;
// MODE 2: as 1, outputs held in regs, h3 -> LDS, W_out epilogue (R17-proven).
template<int MODE>
__global__ __launch_bounds__(LTH, 3) void k_layer(
    const float* __restrict__ x,
    const float* __restrict__ W_in, const float* __restrict__ b_in,
    const __half* __restrict__ hin, const __half* __restrict__ wgt,
    const float* __restrict__ bg, __half* __restrict__ hout,
    const float* __restrict__ W_out, const float* __restrict__ b_out,
    float* __restrict__ outp) {
  __shared__ __half hs[HN * 64];   // 43,520 B -> 3 blocks/CU
  const int tid = threadIdx.x;
  const int tx0 = blockIdx.x * TX;
  const int ty0 = blockIdx.y * TY;
  const int b   = blockIdx.z;

  const int l64 = tid & 63, lm = l64 & 15, lh = l64 >> 4, w = tid >> 6;

  // A fragments (WgT, fp16) + bias C-input (R8-proven)
  half8 af0[4], af1[4];
  v4f cb[4];
#pragma unroll
  for (int ft = 0; ft < 4; ++ft) {
    const __half* wp = wgt + (ft*16 + lm)*64 + lh*8;
    af0[ft] = *(const half8*)wp;
    af1[ft] = *(const half8*)(wp + 32);
    cb[ft] = *(const v4f*)(bg + ft*16 + (lh << 2));
  }

  // ---- staging helpers (chunked) ----
  const float* xb = (MODE == 0) ? (x + (size_t)b*3*NPIX) : nullptr;
  const __half* hb = (MODE != 0) ? (hin + (size_t)b * NPIX * HID) : nullptr;

  auto stage0 = [&](int nlo, int nhi) {   // MODE 0: compute h0, ds_write
    for (int n = nlo + tid; n < nhi; n += LTH) {
      int row = n / HX, col = n - row*HX;
      int gy = ty0 - 1 + row, gx = tx0 - 1 + col;
      __half* hp = &hs[n << 6];
      const int s7 = n & 7;
      if ((unsigned)gy < H_IMG && (unsigned)gx < W_IMG) {
        int gi = (gy << 9) + gx;
        float x0 = xb[gi], x1 = xb[NPIX+gi], x2 = xb[2*NPIX+gi];
#pragma unroll
        for (int c8 = 0; c8 < 8; ++c8) {
          float rr[8];
#pragma unroll
          for (int k = 0; k < 8; ++k) {
            int f = (c8 << 3) + k;
            rr[k] = fmaf(x0, W_in[f], fmaf(x1, W_in[64+f], fmaf(x2, W_in[128+f], b_in[f])));
          }
          uint4 u = make_uint4(pack2(rr[0],rr[1]), pack2(rr[2],rr[3]),
                               pack2(rr[4],rr[5]), pack2(rr[6],rr[7]));
          *(uint4*)(hp + ((c8 ^ s7) << 3)) = u;
        }
      } else {
        uint4 z = make_uint4(0u,0u,0u,0u);
#pragma unroll
        for (int c8 = 0; c8 < 8; ++c8)
          *(uint4*)(hp + ((c8 ^ s7) << 3)) = z;
      }
    }
  };
  auto stage1 = [&](int itlo, int ithi) {  // MODE 1/2: async global_load_lds
    for (int it = itlo + tid; it < ithi; it += LTH) {
      int nl = it >> 3;
      int c8s = (it & 7) ^ (nl & 7);
      int row = nl / HX, col = nl - row*HX;
      int sy = ty0 - 1 + row, sx = tx0 - 1 + col;
      sy = max(0, min(H_IMG-1, sy));
      sx = max(0, min(W_IMG-1, sx));
      const __half* gp = hb + ((size_t)((sy << 9) + sx)) * 64 + (c8s << 3);
      GLOAD16(gp, &hs[it << 3]);
    }
  };

  // ---- stage chunk A (halo rows 0-5) ----
  if (MODE == 0) stage0(0, NA); else stage1(0, NA*8);
  __syncthreads();                 // drain A (B not yet issued)
  // ---- issue chunk B (halo rows 6-9); lands under phase-1 compute ----
  if (MODE == 0) stage0(NA, HN); else stage1(NA*8, HN*8);

  // ---- fused stencil + GEMM, two phases (output rows 0-3, then 4-7) ----
  __half* ho = (MODE != 2) ? (hout + (size_t)b * NPIX * HID) : nullptr;
  uint2 uo[2][2][4];               // MODE 2: packed relu'd h3 per [ph][i][ft]
#pragma unroll
  for (int ph = 0; ph < 2; ++ph) {
#pragma unroll
    for (int i = 0; i < 2; ++i) {
      const int g  = (ph << 3) + (w << 1) + i;   // phase 0: groups 0-7 (rows 0-3)
      const int nn = (g << 4) + lm;
      const int r = nn >> 5, c = nn & 31;
      const int gy = ty0 + r, gx = tx0 + c;
      float ry[3] = {rs1(gy-1,H_IMG), rs1(gy,H_IMG), rs1(gy+1,H_IMG)};
      float rx[3] = {rs1(gx-1,W_IMG), rs1(gx,W_IMG), rs1(gx+1,W_IMG)};
      const float dcc = ry[1]*rx[1];
      float a0[8] = {0,0,0,0,0,0,0,0};
      float a1[8] = {0,0,0,0,0,0,0,0};
#pragma unroll
      for (int dr = 0; dr < 3; ++dr) {
#pragma unroll
        for (int dx = 0; dx < 3; ++dx) {
          int ny = gy - 1 + dr, nx = gx - 1 + dx;
          bool ok = ((unsigned)ny < H_IMG) && ((unsigned)nx < W_IMG);
          float s = ok ? dcc * ry[dr] * rx[dx] : 0.f;
          int nj = (r + dr)*HX + (c + dx);
          const __half* base = &hs[nj << 6];
          uint4 va = *(const uint4*)(base + ((lh ^ (nj & 7)) << 3));
          uint4 vb = *(const uint4*)(base + (((lh + 4) ^ (nj & 7)) << 3));
          fma_mix2(a0[0], a0[1], va.x, s);
          fma_mix2(a0[2], a0[3], va.y, s);
          fma_mix2(a0[4], a0[5], va.z, s);
          fma_mix2(a0[6], a0[7], va.w, s);
          fma_mix2(a1[0], a1[1], vb.x, s);
          fma_mix2(a1[2], a1[3], vb.y, s);
          fma_mix2(a1[4], a1[5], vb.z, s);
          fma_mix2(a1[6], a1[7], vb.w, s);
        }
      }
      half8 b0, b1;
#pragma unroll
      for (int k = 0; k < 8; ++k) { b0[k] = (_Float16)a0[k]; b1[k] = (_Float16)a1[k]; }
      v4f d[4];
#pragma unroll
      for (int ft = 0; ft < 4; ++ft) {
        v4f t = __builtin_amdgcn_mfma_f32_16x16x32_f16(af0[ft], b0, cb[ft], 0, 0, 0);
        d[ft]  = __builtin_amdgcn_mfma_f32_16x16x32_f16(af1[ft], b1, t,     0, 0, 0);
      }
      if (MODE != 2) {
        __half* hp = ho + (size_t)(((ty0 + r) << 9) + tx0 + c) * HID + (lh << 2);
#pragma unroll
        for (int ft = 0; ft < 4; ++ft) {
          uint2 u;
          u.x = pack2(fmaxf(d[ft][0], 0.f), fmaxf(d[ft][1], 0.f));
          u.y = pack2(fmaxf(d[ft][2], 0.f), fmaxf(d[ft][3], 0.f));
          *(uint2*)(hp + ft*16) = u;
        }
      } else {
#pragma unroll
        for (int ft = 0; ft < 4; ++ft) {
          uo[ph][i][ft].x = pack2(fmaxf(d[ft][0], 0.f), fmaxf(d[ft][1], 0.f));
          uo[ph][i][ft].y = pack2(fmaxf(d[ft][2], 0.f), fmaxf(d[ft][3], 0.f));
        }
      }
    }
    if (ph == 0) __syncthreads();   // drain B (landed under phase-1 compute)
  }

  if (MODE == 2) {
    // ---- h3 -> LDS (all halo reads done), then W_out epilogue (R17-proven) ----
    __syncthreads();
#pragma unroll
    for (int ph = 0; ph < 2; ++ph)
#pragma unroll
      for (int i = 0; i < 2; ++i) {
        const int g  = (ph << 3) + (w << 1) + i;
        const int nn = (g << 4) + lm;
        const int s7 = nn & 7;
        __half* hp = &hs[nn << 6];
#pragma unroll
        for (int ft = 0; ft < 4; ++ft) {
          int pos = ft*16 + (lh << 2);
          int c8 = pos >> 3, sub = pos & 7;
          *(uint2*)(hp + ((c8 ^ s7) << 3) + sub) = uo[ph][i][ft];
        }
      }
    __syncthreads();
    const int prow = tid >> 5, pcol = tid & 31;
    const int pgi = ((ty0 + prow) << 9) + tx0 + pcol;
    const __half* hp = &hs[tid << 6];
    const int s7p = tid & 7;
    float p0 = b_out[0], p1 = b_out[1], p2 = b_out[2];
#pragma unroll
    for (int o = 0; o < 8; ++o) {
      half8 v = *(const half8*)(hp + ((o ^ s7p) << 3));
#pragma unroll
      for (int e = 0; e < 8; ++e) {
        const float* wr = W_out + (o*8 + e)*3;   // uniform -> s_load
        float fv = (float)v[e];
        p0 = fmaf(fv, wr[0], p0);
        p1 = fmaf(fv, wr[1], p1);
        p2 = fmaf(fv, wr[2], p2);
      }
    }
    float* ob = outp + (size_t)b*3*NPIX;
    ob[pgi] = p0; ob[NPIX + pgi] = p1; ob[2*NPIX + pgi] = p2;
  }
}

extern "C" void kernel_launch(void* const* d_in, const int* in_sizes, int n_in,
                              void* d_out, int out_size, void* d_ws, size_t ws_size,
                              hipStream_t stream) {
  const float* x     = (const float*)d_in[0];
  // d_in[1] = src, d_in[2] = dst — unused: grid topology is analytic
  const float* W_in  = (const float*)d_in[3];
  const float* b_in  = (const float*)d_in[4];
  const float* Wg    = (const float*)d_in[5];
  const float* bg    = (const float*)d_in[6];
  const float* W_out = (const float*)d_in[7];
  const float* b_out = (const float*)d_in[8];
  float* out = (float*)d_out;

  // WgT fp16 scratch at head of d_out; layers 1-2 read it (stream-ordered,
  // before layer 3 overwrites d_out). Layer-3's slice is copied into hA
  // (dead after layer 2 consumed it) so layer 3 never reads d_out.
  __half* WgT = (__half*)d_out;
  __half* hA = (__half*)d_ws;
  __half* hB = hA + (size_t)BATCH*NPIX*HID;
  __half* w2c = hA;                  // layer-3 weights, in dead hA

  k_wg<<<dim3(48), 256, 0, stream>>>(Wg, WgT);

  dim3 lg(W_IMG/TX, H_IMG/TY, BATCH);   // 16 x 32 x 4
  k_layer<0><<<lg, LTH, 0, stream>>>(x, W_in, b_in, nullptr, WgT, bg, hA,
                                     nullptr, nullptr, nullptr);
  k_layer<1><<<lg, LTH, 0, stream>>>(nullptr, nullptr, nullptr, hA, WgT + 4096, bg + 64, hB,
                                     nullptr, nullptr, nullptr);
  k_prep2<<<dim3(16), 256, 0, stream>>>(WgT + 8192, w2c);
  k_layer<2><<<lg, LTH, 0, stream>>>(nullptr, nullptr, nullptr, hB, w2c, bg + 128, nullptr,
                                     W_out, b_out, out);
}

// Round 20
// 104.333 us; speedup vs baseline: 1.0456x; 1.0456x over previous
//
#include <hip/hip_runtime.h>
#include <hip/hip_fp16.h>

#define H_IMG 256
#define W_IMG 512
#define NPIX  (H_IMG*W_IMG)   // 131072
#define BATCH 4
#define HID   64

#define TX 32
#define TY 8
#define HX (TX+2)   // 34
#define HY (TY+2)   // 10
#define HN (HX*HY)  // 340
#define LTH 256

// LDS: node-major, 64 halfs (128 B) per node, NO pad (global_load_lds writes
// linearly). Bank conflicts handled by XOR swizzle: chunk c8 of node n lives
// at halfs n*64 + ((c8 ^ (n&7))*8). Staging pre-swizzles the GLOBAL source
// chunk so the linear LDS write lands swizzled (rule: both-sides-or-neither).

typedef _Float16 half8 __attribute__((ext_vector_type(8)));
typedef float v4f __attribute__((ext_vector_type(4)));

#define GLOAD16(gp, lp) \
  __builtin_amdgcn_global_load_lds((const __attribute__((address_space(1))) unsigned int*)(gp), \
                                   (__attribute__((address_space(3))) unsigned int*)(lp), 16, 0, 0)

__device__ __forceinline__ float rs1(int v, int n) {
  return rsqrtf((float)(3 - (v==0) - (v==(n-1))));   // finite for any v
}
__device__ __forceinline__ float dinvf(int y, int x) {
  int cy = 3 - (y==0) - (y==(H_IMG-1));
  int cx = 3 - (x==0) - (x==(W_IMG-1));
  return rsqrtf((float)(cy*cx));
}

__device__ __forceinline__ unsigned pack2(float a, float b) {
  __half2 h = __floats2half2_rn(a, b);
  return *reinterpret_cast<unsigned*>(&h);
}

// acc{L,H} += fp16{lo,hi}(hv) * s   — forced v_fma_mix_f32 (R16-proven)
__device__ __forceinline__ void fma_mix2(float& accL, float& accH, unsigned hv, float s) {
  asm("v_fma_mix_f32 %0, %2, %3, %0 op_sel:[0,0,0] op_sel_hi:[1,0,0]\n\t"
      "v_fma_mix_f32 %1, %2, %3, %1 op_sel:[1,0,0] op_sel_hi:[1,0,0]"
      : "+v"(accL), "+v"(accH)
      : "v"(hv), "v"(s));
}

// WgT[l][f][k] = fp16(Wg[l][k][f])   (R2/R8-proven)
__global__ void k_wg(const float* __restrict__ Wg, __half* __restrict__ WgT) {
  int idx = blockIdx.x * 256 + threadIdx.x;          // 3*64*64 = 12288
  int l = idx >> 12, rem = idx & 4095;
  int f = rem >> 6, k = rem & 63;
  WgT[idx] = __float2half(Wg[(l << 12) + (k << 6) + f]);
}

// Copy layer-3 WgT slice (4096 halfs) from d_out head into dead hA region
// (layer 3 writes d_out, so it must not read weights from d_out).  (R17-proven)
__global__ void k_prep2(const __half* __restrict__ src, __half* __restrict__ dst) {
  int idx = blockIdx.x * 256 + threadIdx.x;
  if (idx < 4096) dst[idx] = src[idx];
}

// One GCN layer (32x8 tile, 256 threads).
// MODE 0: build h0 from x on the fly; FUSED stencil+GEMM (1 barrier)
// MODE 1: async-stage from hin;       FUSED stencil+GEMM (1 barrier)
// MODE 2: async-stage from hin; R17-proven multi-phase body + W_out epilogue
template<int MODE>
__global__ __launch_bounds__(LTH, 3) void k_layer(
    const float* __restrict__ x,
    const float* __restrict__ W_in, const float* __restrict__ b_in,
    const __half* __restrict__ hin, const __half* __restrict__ wgt,
    const float* __restrict__ bg, __half* __restrict__ hout,
    const float* __restrict__ W_out, const float* __restrict__ b_out,
    float* __restrict__ outp) {
  __shared__ __half hs[HN * 64];   // 43,520 B -> 3 blocks/CU
  const int tid = threadIdx.x;
  const int tx0 = blockIdx.x * TX;
  const int ty0 = blockIdx.y * TY;
  const int b   = blockIdx.z;

  const int l64 = tid & 63, lm = l64 & 15, lh = l64 >> 4, w = tid >> 6;

  // A fragments (WgT, fp16) + bias C-input (R8-proven)
  half8 af0[4], af1[4];
  v4f cb[4];
#pragma unroll
  for (int ft = 0; ft < 4; ++ft) {
    const __half* wp = wgt + (ft*16 + lm)*64 + lh*8;
    af0[ft] = *(const half8*)wp;
    af1[ft] = *(const half8*)(wp + 32);
    cb[ft] = *(const v4f*)(bg + ft*16 + (lh << 2));
  }

  // ---- staging ----
  if (MODE == 0) {
    // h0 halo built on the fly from x; swizzled ds-writes; OOB -> 0
    const float* xb = x + (size_t)b*3*NPIX;
    for (int n = tid; n < HN; n += LTH) {
      int row = n / HX, col = n - row*HX;
      int gy = ty0 - 1 + row, gx = tx0 - 1 + col;
      __half* hp = &hs[n << 6];
      const int s7 = n & 7;
      if ((unsigned)gy < H_IMG && (unsigned)gx < W_IMG) {
        int gi = (gy << 9) + gx;
        float x0 = xb[gi], x1 = xb[NPIX+gi], x2 = xb[2*NPIX+gi];
#pragma unroll
        for (int c8 = 0; c8 < 8; ++c8) {
          float rr[8];
#pragma unroll
          for (int k = 0; k < 8; ++k) {
            int f = (c8 << 3) + k;
            rr[k] = fmaf(x0, W_in[f], fmaf(x1, W_in[64+f], fmaf(x2, W_in[128+f], b_in[f])));
          }
          uint4 u = make_uint4(pack2(rr[0],rr[1]), pack2(rr[2],rr[3]),
                               pack2(rr[4],rr[5]), pack2(rr[6],rr[7]));
          *(uint4*)(hp + ((c8 ^ s7) << 3)) = u;
        }
      } else {
        uint4 z = make_uint4(0u,0u,0u,0u);
#pragma unroll
        for (int c8 = 0; c8 < 8; ++c8)
          *(uint4*)(hp + ((c8 ^ s7) << 3)) = z;
      }
    }
  } else {
    // async staging: back-to-back global_load_lds (16B); clamped addrs,
    // OOB handled by zeroed stencil scales. (R11-proven)
    const __half* hb = hin + (size_t)b * NPIX * HID;
    for (int it = tid; it < HN*8; it += LTH) {
      int nl = it >> 3;
      int c8s = (it & 7) ^ (nl & 7);
      int row = nl / HX, col = nl - row*HX;
      int sy = ty0 - 1 + row, sx = tx0 - 1 + col;
      sy = max(0, min(H_IMG-1, sy));
      sx = max(0, min(W_IMG-1, sx));
      const __half* gp = hb + ((size_t)((sy << 9) + sx)) * 64 + (c8s << 3);
      GLOAD16(gp, &hs[it << 3]);
    }
  }
  __syncthreads();   // compiler drains vmcnt before barrier

  if (MODE != 2) {
    // ================= FUSED stencil + GEMM (single-barrier layer) =========
    // Lane computes stencil s for node nn=(g*16+lm), octets lh & lh+4 —
    // exactly its MFMA B-fragment — straight from the halo. No s-spill, no
    // barriers; stencil VALU of group i+1 overlaps MFMA of group i.
    __half* ho = hout + (size_t)b * NPIX * HID;
#pragma unroll
    for (int i = 0; i < 4; ++i) {
      const int g  = (w << 2) + i;       // node group: 16 nodes
      const int nn = (g << 4) + lm;      // this lane's node
      const int r = nn >> 5, c = nn & 31;
      const int gy = ty0 + r, gx = tx0 + c;
      float ry[3] = {rs1(gy-1,H_IMG), rs1(gy,H_IMG), rs1(gy+1,H_IMG)};
      float rx[3] = {rs1(gx-1,W_IMG), rs1(gx,W_IMG), rs1(gx+1,W_IMG)};
      const float dcc = ry[1]*rx[1];
      float a0[8] = {0,0,0,0,0,0,0,0};   // octet lh   (features lh*8+e)
      float a1[8] = {0,0,0,0,0,0,0,0};   // octet lh+4 (features 32+lh*8+e)
#pragma unroll
      for (int dr = 0; dr < 3; ++dr) {
#pragma unroll
        for (int dx = 0; dx < 3; ++dx) {
          int ny = gy - 1 + dr, nx = gx - 1 + dx;
          bool ok = ((unsigned)ny < H_IMG) && ((unsigned)nx < W_IMG);
          float s = ok ? dcc * ry[dr] * rx[dx] : 0.f;
          int nj = (r + dr)*HX + (c + dx);
          const __half* base = &hs[nj << 6];
          uint4 va = *(const uint4*)(base + ((lh ^ (nj & 7)) << 3));
          uint4 vb = *(const uint4*)(base + (((lh + 4) ^ (nj & 7)) << 3));
          fma_mix2(a0[0], a0[1], va.x, s);
          fma_mix2(a0[2], a0[3], va.y, s);
          fma_mix2(a0[4], a0[5], va.z, s);
          fma_mix2(a0[6], a0[7], va.w, s);
          fma_mix2(a1[0], a1[1], vb.x, s);
          fma_mix2(a1[2], a1[3], vb.y, s);
          fma_mix2(a1[4], a1[5], vb.z, s);
          fma_mix2(a1[6], a1[7], vb.w, s);
        }
      }
      half8 b0, b1;
#pragma unroll
      for (int k = 0; k < 8; ++k) { b0[k] = (_Float16)a0[k]; b1[k] = (_Float16)a1[k]; }
      v4f d[4];
#pragma unroll
      for (int ft = 0; ft < 4; ++ft) {
        v4f t = __builtin_amdgcn_mfma_f32_16x16x32_f16(af0[ft], b0, cb[ft], 0, 0, 0);
        d[ft]  = __builtin_amdgcn_mfma_f32_16x16x32_f16(af1[ft], b1, t,     0, 0, 0);
      }
      // lane holds features ft*16 + lh*4 + e of node nn
      __half* hp = ho + (size_t)(((ty0 + r) << 9) + tx0 + c) * HID + (lh << 2);
#pragma unroll
      for (int ft = 0; ft < 4; ++ft) {
        uint2 u;
        u.x = pack2(fmaxf(d[ft][0], 0.f), fmaxf(d[ft][1], 0.f));
        u.y = pack2(fmaxf(d[ft][2], 0.f), fmaxf(d[ft][3], 0.f));
        *(uint2*)(hp + ft*16) = u;
      }
    }
    return;
  }

  // ================= MODE 2: R17-proven multi-phase body =================
  {
    const int lx = tid & 31, ly = tid >> 5;
    const int gy = ty0 + ly, gx = tx0 + lx;
    const float dc = dinvf(gy, gx);
    float sc[9];
    int   nbn[9];
#pragma unroll
    for (int r = 0; r < 3; ++r)
#pragma unroll
      for (int c = 0; c < 3; ++c) {
        int ny = gy - 1 + r, nx = gx - 1 + c;
        bool ok = ((unsigned)ny < H_IMG) && ((unsigned)nx < W_IMG);
        sc[r*3+c] = ok ? dc * dinvf(ny, nx) : 0.f;
        nbn[r*3+c] = (ly + r)*HX + lx + c;
      }
    half8 sreg[8];
#pragma unroll
    for (int ch = 0; ch < 8; ++ch) {
      float acc[8] = {0.f,0.f,0.f,0.f,0.f,0.f,0.f,0.f};
#pragma unroll
      for (int j = 0; j < 9; ++j) {
        int nj = nbn[j];
        uint4 v = *(const uint4*)&hs[(nj << 6) + (((ch ^ (nj & 7))) << 3)];
        float s = sc[j];
        fma_mix2(acc[0], acc[1], v.x, s);
        fma_mix2(acc[2], acc[3], v.y, s);
        fma_mix2(acc[4], acc[5], v.z, s);
        fma_mix2(acc[6], acc[7], v.w, s);
      }
      half8 o;
#pragma unroll
      for (int k = 0; k < 8; ++k) o[k] = (_Float16)acc[k];
      sreg[ch] = o;
    }
    __syncthreads();

    {
      __half* hp = &hs[tid << 6];
      const int s7 = tid & 7;
#pragma unroll
      for (int ch = 0; ch < 8; ++ch)
        *(half8*)(hp + ((ch ^ s7) << 3)) = sreg[ch];
    }
    __syncthreads();

#pragma unroll
    for (int i = 0; i < 4; ++i) {
      int g  = (w << 2) + i;
      int nn = (g << 4) + lm;
      const int s7 = nn & 7;
      const __half* np = &hs[nn << 6];
      half8 b0 = *(const half8*)(np + ((lh ^ s7) << 3));
      half8 b1 = *(const half8*)(np + (((lh + 4) ^ s7) << 3));
      v4f d[4];
#pragma unroll
      for (int ft = 0; ft < 4; ++ft) {
        v4f t = __builtin_amdgcn_mfma_f32_16x16x32_f16(af0[ft], b0, cb[ft], 0, 0, 0);
        d[ft]  = __builtin_amdgcn_mfma_f32_16x16x32_f16(af1[ft], b1, t,     0, 0, 0);
      }
      // relu(h3) -> LDS (this wave's nodes only; program order protects RAW)
      __half* hp = &hs[nn << 6];
#pragma unroll
      for (int ft = 0; ft < 4; ++ft) {
        int pos = ft*16 + (lh << 2);
        int c8 = pos >> 3, sub = pos & 7;
        uint2 u;
        u.x = pack2(fmaxf(d[ft][0], 0.f), fmaxf(d[ft][1], 0.f));
        u.y = pack2(fmaxf(d[ft][2], 0.f), fmaxf(d[ft][3], 0.f));
        *(uint2*)(hp + ((c8 ^ s7) << 3) + sub) = u;
      }
    }

    // epilogue: out = h3 @ W_out + b_out, LDS-sourced (R17-proven)
    __syncthreads();
    const int prow = tid >> 5, pcol = tid & 31;
    const int pgi = ((ty0 + prow) << 9) + tx0 + pcol;
    const __half* hp = &hs[tid << 6];
    const int s7p = tid & 7;
    float p0 = b_out[0], p1 = b_out[1], p2 = b_out[2];
#pragma unroll
    for (int o = 0; o < 8; ++o) {
      half8 v = *(const half8*)(hp + ((o ^ s7p) << 3));
#pragma unroll
      for (int e = 0; e < 8; ++e) {
        const float* wr = W_out + (o*8 + e)*3;   // uniform -> s_load
        float fv = (float)v[e];
        p0 = fmaf(fv, wr[0], p0);
        p1 = fmaf(fv, wr[1], p1);
        p2 = fmaf(fv, wr[2], p2);
      }
    }
    float* ob = outp + (size_t)b*3*NPIX;
    ob[pgi] = p0; ob[NPIX + pgi] = p1; ob[2*NPIX + pgi] = p2;
  }
}

extern "C" void kernel_launch(void* const* d_in, const int* in_sizes, int n_in,
                              void* d_out, int out_size, void* d_ws, size_t ws_size,
                              hipStream_t stream) {
  const float* x     = (const float*)d_in[0];
  // d_in[1] = src, d_in[2] = dst — unused: grid topology is analytic
  const float* W_in  = (const float*)d_in[3];
  const float* b_in  = (const float*)d_in[4];
  const float* Wg    = (const float*)d_in[5];
  const float* bg    = (const float*)d_in[6];
  const float* W_out = (const float*)d_in[7];
  const float* b_out = (const float*)d_in[8];
  float* out = (float*)d_out;

  // WgT fp16 scratch at head of d_out; layers 1-2 read it (stream-ordered,
  // before layer 3 overwrites d_out). Layer-3's slice is copied into hA
  // (dead after layer 2 consumed it) so layer 3 never reads d_out.
  __half* WgT = (__half*)d_out;
  __half* hA = (__half*)d_ws;
  __half* hB = hA + (size_t)BATCH*NPIX*HID;
  __half* w2c = hA;                  // layer-3 weights, in dead hA

  k_wg<<<dim3(48), 256, 0, stream>>>(Wg, WgT);

  dim3 lg(W_IMG/TX, H_IMG/TY, BATCH);   // 16 x 32 x 4
  k_layer<0><<<lg, LTH, 0, stream>>>(x, W_in, b_in, nullptr, WgT, bg, hA,
                                     nullptr, nullptr, nullptr);
  k_layer<1><<<lg, LTH, 0, stream>>>(nullptr, nullptr, nullptr, hA, WgT + 4096, bg + 64, hB,
                                     nullptr, nullptr, nullptr);
  k_prep2<<<dim3(16), 256, 0, stream>>>(WgT + 8192, w2c);
  k_layer<2><<<lg, LTH, 0, stream>>>(nullptr, nullptr, nullptr, hB, w2c, bg + 128, nullptr,
                                     W_out, b_out, out);
}